// Round 4
// baseline (587.651 us; speedup 1.0000x reference)
//
#include <hip/hip_runtime.h>
#include <math.h>

#define RNUM 14
#define NNODE 100000
#define ENUM 1600000
#define NBINS2 (NNODE * 16)               // key: dst*16 + rel
#define TILE 2048
#define NBSC ((NBINS2 + TILE - 1) / TILE) // 782
#define NT16 (NNODE / 16)                 // 6250
#define NTB ((NT16 + 15) / 16)            // 391

typedef __attribute__((ext_vector_type(8))) short bf16x8;
typedef __attribute__((ext_vector_type(4))) float f32x4;

__device__ inline unsigned short f2bf(float f) {
    unsigned u = __builtin_bit_cast(unsigned, f);
    u += 0x7FFF + ((u >> 16) & 1);
    return (unsigned short)(u >> 16);
}
__device__ inline float bf2f(unsigned short h) {
    unsigned u = ((unsigned)h) << 16;
    return __builtin_bit_cast(float, u);
}
__device__ inline int uload(const int* __restrict__ p) {
    return __builtin_amdgcn_readfirstlane(*p);
}

// ---------------- counting sort (key = dst*16 + rel) ----------------
__global__ void hist_k(const int* __restrict__ dst, const int* __restrict__ et,
                       int* __restrict__ counts) {
    int e = blockIdx.x * 256 + threadIdx.x;
    if (e >= ENUM) return;
    atomicAdd(&counts[dst[e] * 16 + et[e]], 1);
}

__global__ void scan_blocks_k(const int* __restrict__ counts, int* __restrict__ offs,
                              int* __restrict__ partials) {
    __shared__ int tsum[256];
    int blk = blockIdx.x, t = threadIdx.x;
    int base = blk * TILE + t * 8;
    int v[8];
    int s = 0;
#pragma unroll
    for (int j = 0; j < 8; j++) {
        int idx = base + j;
        v[j] = (idx < NBINS2) ? counts[idx] : 0;
        s += v[j];
    }
    tsum[t] = s;
    __syncthreads();
#pragma unroll
    for (int off = 1; off < 256; off <<= 1) {
        int val = (t >= off) ? tsum[t - off] : 0;
        __syncthreads();
        if (t >= off) tsum[t] += val;
        __syncthreads();
    }
    int run = tsum[t] - s;
#pragma unroll
    for (int j = 0; j < 8; j++) {
        int idx = base + j;
        if (idx < NBINS2) offs[idx] = run;
        run += v[j];
    }
    if (t == 255) partials[blk] = tsum[255];
}

__global__ void scan_partials_k(int* partials) {
    __shared__ int sh[1024];
    int t = threadIdx.x;
    sh[t] = (t < NBSC) ? partials[t] : 0;
    __syncthreads();
    for (int off = 1; off < 1024; off <<= 1) {
        int v = (t >= off) ? sh[t - off] : 0;
        __syncthreads();
        sh[t] += v;
        __syncthreads();
    }
    if (t < NBSC) partials[t] = (t == 0) ? 0 : sh[t - 1];
}

__global__ void scan_add_k(int* __restrict__ offs, const int* __restrict__ partials,
                           int* __restrict__ cursor) {
    int blk = blockIdx.x, t = threadIdx.x;
    int add = partials[blk];
    int base = blk * TILE + t * 8;
#pragma unroll
    for (int j = 0; j < 8; j++) {
        int idx = base + j;
        if (idx < NBINS2) {
            int v = offs[idx] + add;
            offs[idx] = v;
            cursor[idx] = v;
        }
    }
    if (blk == 0 && t == 0) offs[NBINS2] = ENUM;
}

// stores global H-row index r*N+src so agg needs no slab logic
__global__ void scatter_k(const int* __restrict__ src, const int* __restrict__ dst,
                          const int* __restrict__ et, int* __restrict__ cursor,
                          int* __restrict__ ssrc) {
    int e = blockIdx.x * 256 + threadIdx.x;
    if (e >= ENUM) return;
    int r = et[e];
    int key = dst[e] * 16 + r;
    int p = atomicAdd(&cursor[key], 1);
    ssrc[p] = r * NNODE + src[e];
}

// ---------------- weight pre-pack into MFMA fragment order ----------------
// F[idx]: idx = r*4096 + kh*2048 + ot*512 + lane*8 + j holds W[k][c]
// with k = kh*32+(lane>>4)*8+j, c = ot*16+(lane&15).
// Used as the A-operand (A = W^T): A[row=c][k] = W[k][c] (A/B frag layouts mirror).
__global__ void wfrag1_k(const float* __restrict__ w1, unsigned short* __restrict__ F) {
    int idx = blockIdx.x * 256 + threadIdx.x;
    if (idx >= RNUM * 4096) return;
    int j = idx & 7, lane = (idx >> 3) & 63, ot = (idx >> 9) & 3, kh = (idx >> 11) & 1, r = idx >> 12;
    int k = kh * 32 + (lane >> 4) * 8 + j;
    int c = ot * 16 + (lane & 15);
    int bi = k >> 3, bo = c >> 3;
    float v = 0.f;
    if (bi == bo) v = w1[((r * 8 + bi) * 8 + (k & 7)) * 8 + (c & 7)];
    F[idx] = f2bf(v);
}

__global__ void wfrag2_k(const float* __restrict__ comp2, const float* __restrict__ bases2,
                         unsigned short* __restrict__ F) {
    int idx = blockIdx.x * 256 + threadIdx.x;
    if (idx >= RNUM * 4096) return;
    int j = idx & 7, lane = (idx >> 3) & 63, ot = (idx >> 9) & 3, kh = (idx >> 11) & 1, r = idx >> 12;
    int k = kh * 32 + (lane >> 4) * 8 + j;
    int c = ot * 16 + (lane & 15);
    float s = 0.f;
#pragma unroll
    for (int b = 0; b < 8; b++) s += comp2[r * 8 + b] * bases2[(b * 64 + k) * 64 + c];
    F[idx] = f2bf(s);
}

__global__ void rootfrag_k(const float* __restrict__ W, unsigned short* __restrict__ F) {
    int idx = blockIdx.x * 256 + threadIdx.x;
    if (idx >= 4096) return;
    int j = idx & 7, lane = (idx >> 3) & 63, ot = (idx >> 9) & 3, kh = (idx >> 11) & 1;
    int k = kh * 32 + (lane >> 4) * 8 + j;
    int c = ot * 16 + (lane & 15);
    F[idx] = f2bf(W[k * 64 + c]);
}

__global__ void xb_k(const float* __restrict__ x, unsigned short* __restrict__ xb) {
    int idx = blockIdx.x * 256 + threadIdx.x;
    if (idx >= NNODE * 64) return;
    xb[idx] = f2bf(x[idx]);
}

// ---------------- GEMM: Y[r][n][:] = A[n][:] @ W[r]  via C = W^T * X^T ----------------
__global__ void __launch_bounds__(256) gemm_k(const unsigned short* __restrict__ A,
                                              const unsigned short* __restrict__ F,
                                              unsigned short* __restrict__ Y) {
    int tb = blockIdx.x % NTB;
    int r  = blockIdx.x / NTB;
    int wave = threadIdx.x >> 6, lane = threadIdx.x & 63;
    const unsigned short* Fr = F + (size_t)r * 4096;
    bf16x8 wf[2][4];
#pragma unroll
    for (int kh = 0; kh < 2; kh++)
#pragma unroll
        for (int ot = 0; ot < 4; ot++)
            wf[kh][ot] = *(const bf16x8*)(Fr + ((kh * 4 + ot) * 64 + lane) * 8);
    int node16 = lane & 15;
    int kcol = (lane >> 4) * 8;
    int g = lane >> 4;
    for (int s = 0; s < 4; s++) {
        int nt = tb * 16 + wave * 4 + s;
        if (nt >= NT16) break;
        int nbase = nt * 16;
        // B-operand: B[k][col=node] — lane loads x-row of node (lane&15), features kcol..kcol+7
        const unsigned short* Arow = A + (size_t)(nbase + node16) * 64;
        bf16x8 b0 = *(const bf16x8*)(Arow + kcol);
        bf16x8 b1 = *(const bf16x8*)(Arow + 32 + kcol);
        f32x4 acc[4];
#pragma unroll
        for (int ot = 0; ot < 4; ot++) {
            acc[ot] = (f32x4){0.f, 0.f, 0.f, 0.f};
            acc[ot] = __builtin_amdgcn_mfma_f32_16x16x32_bf16(wf[0][ot], b0, acc[ot], 0, 0, 0);
            acc[ot] = __builtin_amdgcn_mfma_f32_16x16x32_bf16(wf[1][ot], b1, acc[ot], 0, 0, 0);
        }
        // C: col = node (lane&15), row = feature ot*16 + g*4 + j  -> 4 consecutive feats/lane
        unsigned short* Yr = Y + ((size_t)r * NNODE + nbase) * 64;
#pragma unroll
        for (int ot = 0; ot < 4; ot++) {
            unsigned p0 = (unsigned)f2bf(acc[ot][0]) | ((unsigned)f2bf(acc[ot][1]) << 16);
            unsigned p1 = (unsigned)f2bf(acc[ot][2]) | ((unsigned)f2bf(acc[ot][3]) << 16);
            uint2 pv; pv.x = p0; pv.y = p1;
            *(uint2*)(Yr + (size_t)node16 * 64 + ot * 16 + g * 4) = pv;
        }
    }
}

// ---------------- aggregation: flat pipelined edge loop, one wave per node ----------------
// flags: 1=first chunk, 2=last chunk, 4=layer1 (relu + bf16 out to x1b)
template <int FULL>
__global__ void __launch_bounds__(256) agg_k(
    const unsigned short* __restrict__ H, const int* __restrict__ offs,
    const int* __restrict__ ssrc, const unsigned short* __restrict__ xrootb,
    const float* __restrict__ bias, float* __restrict__ aggbuf,
    unsigned short* __restrict__ x1b, float* __restrict__ outf,
    int r0, int rcnt, int flags) {
    int wv = threadIdx.x >> 6, lane = threadIdx.x & 63;
    int d = __builtin_amdgcn_readfirstlane(blockIdx.x * 4 + wv);
    if (d >= NNODE) return;
    float msum = 0.f;

    if constexpr (FULL) {
        const int base = d * 16;  // r0 == 0
        int4 q0 = *(const int4*)(offs + base);
        int4 q1 = *(const int4*)(offs + base + 4);
        int4 q2 = *(const int4*)(offs + base + 8);
        int4 q3 = *(const int4*)(offs + base + 12);  // .z = offs[base+14] = end
        int e0 = q0.x;
        int eend = q3.z;
        float m = -INFINITY;
        for (int cb = e0; cb < eend; cb += 64) {
            int idx = cb + lane;
            int cidx = (idx < eend) ? idx : eend - 1;
            int sv = ssrc[cidx];
            // flush mask from 13 interior boundaries
            unsigned long long mask = 0;
#define ADDB(bb) { int kk_ = (bb) - cb; \
                   if (kk_ >= 0 && kk_ < 64 && (bb) > e0) mask |= 1ull << kk_; }
            ADDB(q0.y) ADDB(q0.z) ADDB(q0.w)
            ADDB(q1.x) ADDB(q1.y) ADDB(q1.z) ADDB(q1.w)
            ADDB(q2.x) ADDB(q2.y) ADDB(q2.z) ADDB(q2.w)
            ADDB(q3.x) ADDB(q3.y)
#undef ADDB
            int n = eend - cb; if (n > 64) n = 64;
            for (int k0 = 0; k0 < n; k0 += 8) {
                float h[8];
#pragma unroll
                for (int u = 0; u < 8; u++) {
                    int kk = k0 + u;
                    int kc = (kk < n) ? kk : n - 1;   // tail dups -> merged fetch
                    int s = __shfl(sv, kc, 64);
                    h[u] = bf2f(H[(size_t)s * 64 + lane]);
                }
#pragma unroll
                for (int u = 0; u < 8; u++) {
                    int kk = k0 + u;
                    if (kk >= n) break;
                    bool fl = (mask >> kk) & 1;
                    msum += fl ? m : 0.f;
                    m = fl ? h[u] : fmaxf(m, h[u]);
                }
            }
        }
        if (eend > e0) msum += m;
    } else {
        // chunked fallback (rarely used): per-segment loop, rows offset by r0*NNODE
        const int base = d * 16 + r0;
        for (int j = 0; j < rcnt; j++) {
            int e = uload(offs + base + j);
            int ee = uload(offs + base + j + 1);
            if (e >= ee) continue;
            float m = -INFINITY;
            for (; e < ee; e++) {
                int row = uload(ssrc + e) - r0 * NNODE;
                m = fmaxf(m, bf2f(H[(size_t)row * 64 + lane]));
            }
            msum += m;
        }
    }

    size_t o = (size_t)d * 64 + lane;
    if (!(flags & 1)) msum += aggbuf[o];
    if (!(flags & 2)) { aggbuf[o] = msum; return; }
    float v = msum + bf2f(xrootb[o]) + bias[lane];
    if (flags & 4) x1b[o] = f2bf(fmaxf(v, 0.f));
    else outf[o] = v;
}

extern "C" void kernel_launch(void* const* d_in, const int* in_sizes, int n_in,
                              void* d_out, int out_size, void* d_ws, size_t ws_size,
                              hipStream_t stream) {
    const float* x      = (const float*)d_in[0];
    const int*   ei     = (const int*)d_in[1];
    const int*   et     = (const int*)d_in[2];
    const float* w1     = (const float*)d_in[3];
    const float* root1  = (const float*)d_in[4];
    const float* bias1  = (const float*)d_in[5];
    const float* comp2  = (const float*)d_in[6];
    const float* bases2 = (const float*)d_in[7];
    const float* root2  = (const float*)d_in[8];
    const float* bias2  = (const float*)d_in[9];
    const int* srcv = ei;
    const int* dstv = ei + ENUM;
    float* out = (float*)d_out;

    char* w = (char*)d_ws;
    size_t off = 0;
    auto alloc = [&](size_t bytes) -> void* {
        void* p = w + off;
        off += (bytes + 255) & ~(size_t)255;
        return p;
    };
    int*   offs     = (int*)alloc((NBINS2 + 1) * sizeof(int));
    int*   cursor   = (int*)alloc((size_t)NBINS2 * sizeof(int));
    int*   partials = (int*)alloc(1024 * sizeof(int));
    int*   ssrc     = (int*)alloc((size_t)ENUM * sizeof(int));
    unsigned short* xb     = (unsigned short*)alloc((size_t)NNODE * 64 * 2); // also x1b
    unsigned short* xrootb = (unsigned short*)alloc((size_t)NNODE * 64 * 2);
    float*          aggbuf = (float*)alloc((size_t)NNODE * 64 * 4);
    unsigned short* frag1  = (unsigned short*)alloc((size_t)RNUM * 4096 * 2);
    unsigned short* frag2  = (unsigned short*)alloc((size_t)RNUM * 4096 * 2);
    unsigned short* rootf1 = (unsigned short*)alloc(4096 * 2);
    unsigned short* rootf2 = (unsigned short*)alloc(4096 * 2);
    size_t fixed = off;
    if (fixed > ws_size) return;
    size_t slab = ((size_t)NNODE * 64 * 2 + 255) & ~(size_t)255;
    int r_per = (int)((ws_size - fixed) / slab);
    if (r_per < 1) return;
    if (r_per > RNUM) r_per = RNUM;
    unsigned short* H = (unsigned short*)alloc((size_t)r_per * slab);

    hipMemsetAsync(cursor, 0, (size_t)NBINS2 * sizeof(int), stream);

    hist_k<<<(ENUM + 255) / 256, 256, 0, stream>>>(dstv, et, cursor);
    scan_blocks_k<<<NBSC, 256, 0, stream>>>(cursor, offs, partials);
    scan_partials_k<<<1, 1024, 0, stream>>>(partials);
    scan_add_k<<<NBSC, 256, 0, stream>>>(offs, partials, cursor);
    scatter_k<<<(ENUM + 255) / 256, 256, 0, stream>>>(srcv, dstv, et, cursor, ssrc);

    wfrag1_k<<<(RNUM * 4096 + 255) / 256, 256, 0, stream>>>(w1, frag1);
    wfrag2_k<<<(RNUM * 4096 + 255) / 256, 256, 0, stream>>>(comp2, bases2, frag2);
    rootfrag_k<<<16, 256, 0, stream>>>(root1, rootf1);
    rootfrag_k<<<16, 256, 0, stream>>>(root2, rootf2);
    xb_k<<<(NNODE * 64 + 255) / 256, 256, 0, stream>>>(x, xb);

    int nch = (RNUM + r_per - 1) / r_per;
    int aggGrid = NNODE / 4;  // 4 nodes (waves) per block

    // ---- layer 1 ----
    gemm_k<<<NTB, 256, 0, stream>>>(xb, rootf1, xrootb);
    for (int c = 0; c < nch; c++) {
        int r0 = c * r_per;
        int rcnt = (RNUM - r0 < r_per) ? (RNUM - r0) : r_per;
        gemm_k<<<rcnt * NTB, 256, 0, stream>>>(xb, frag1 + (size_t)r0 * 4096, H);
        int flags = 4 | (c == 0 ? 1 : 0) | (c == nch - 1 ? 2 : 0);
        if (rcnt == RNUM)
            agg_k<1><<<aggGrid, 256, 0, stream>>>(H, offs, ssrc, xrootb, bias1, aggbuf,
                                                  xb, out, r0, rcnt, flags);
        else
            agg_k<0><<<aggGrid, 256, 0, stream>>>(H, offs, ssrc, xrootb, bias1, aggbuf,
                                                  xb, out, r0, rcnt, flags);
    }

    // ---- layer 2 ----
    gemm_k<<<NTB, 256, 0, stream>>>(xb, rootf2, xrootb);
    for (int c = 0; c < nch; c++) {
        int r0 = c * r_per;
        int rcnt = (RNUM - r0 < r_per) ? (RNUM - r0) : r_per;
        gemm_k<<<rcnt * NTB, 256, 0, stream>>>(xb, frag2 + (size_t)r0 * 4096, H);
        int flags = (c == 0 ? 1 : 0) | (c == nch - 1 ? 2 : 0);
        if (rcnt == RNUM)
            agg_k<1><<<aggGrid, 256, 0, stream>>>(H, offs, ssrc, xrootb, bias2, aggbuf,
                                                  xb, out, r0, rcnt, flags);
        else
            agg_k<0><<<aggGrid, 256, 0, stream>>>(H, offs, ssrc, xrootb, bias2, aggbuf,
                                                  xb, out, r0, rcnt, flags);
    }
}